// Round 2
// baseline (10686.063 us; speedup 1.0000x reference)
//
#include <hip/hip_runtime.h>

typedef __bf16 bf16x8 __attribute__((ext_vector_type(8)));
typedef float  f32x4  __attribute__((ext_vector_type(4)));
typedef unsigned short u16;
typedef unsigned int   u32;
typedef unsigned long long u64;

#define NB 128      // batch
#define NT 1024     // time steps
#define NF 128      // input features
#define NH 256      // hidden units (both layers)
#define NG 1024     // 4*NH gate columns
#define M_ROWS (NB*NT)

__device__ __forceinline__ u16 f2bf(float f) {
  union { float f; u32 u; } c; c.f = f;
  u32 u = c.u;
  return (u16)((u + 0x7fffu + ((u >> 16) & 1u)) >> 16);   // RNE
}

__device__ __forceinline__ float sigm(float x) { return 1.f / (1.f + __expf(-x)); }
__device__ __forceinline__ float tanh_(float x) { return 1.f - 2.f / (1.f + __expf(2.f * x)); }

__device__ __forceinline__ f32x4 mm(bf16x8 a, bf16x8 b, f32x4 c) {
  return __builtin_amdgcn_mfma_f32_16x16x32_bf16(a, b, c, 0, 0, 0);
}

// ---------------------------------------------------------------------------
// prep: zero the spin counters.
// ---------------------------------------------------------------------------
__global__ void prep(u32* __restrict__ flags) {
  int i = threadIdx.x;
  if (i < 32) flags[i] = 0;
}

// ---------------------------------------------------------------------------
// lstm_scan: one layer, input projection FUSED into the scan.
// 32 blocks = 8 groups (16 batch rows, XCD-aligned: g = bid&7) x 4 WGs
// (unit-quarter j = bid>>3). Each WG: 256 threads = 4 waves (1 wave/SIMD,
// 512-VGPR budget). Wave w == Keras gate w (i,f,cbar,o).
// Resident in VGPRs per wave: U-slice frags [256K x 64cols] (128 VGPR) and
// W-slice frags [KIN x 64cols] (KIN/2 VGPR).
// Per step: gates = x_t@W (issued BEFORE the spin; no h dependence)
//                 + h_{t-1}@U + bias; pointwise; publish h.
// Cross-WG h exchange: AGENT-scope atomics + monotonic counter, 2-parity
// hbuf. c state stays fp32 in registers. Spin has a bailout (never hangs).
// ---------------------------------------------------------------------------
template<int KIN, bool XF32>
__global__ __launch_bounds__(256, 1) void lstm_scan(
    const float* __restrict__ U,     // [NH, NG]
    const float* __restrict__ W,     // [KIN, NG]
    const float* __restrict__ bias,  // [NG]
    const float* __restrict__ xf,    // [NB, NT, KIN] fp32   (XF32)
    const u16*   __restrict__ xh,    // [NB, NT, KIN] bf16   (!XF32)
    u16* __restrict__ hbuf,          // [2][8][16][NH] bf16
    u32* __restrict__ flags,         // [8] counters (this layer)
    u16* __restrict__ h_seq,         // [NB*NT, NH] bf16 or null
    float* __restrict__ hlast)       // [NB, NH] f32 or null
{
  const int tid  = threadIdx.x;
  const int lane = tid & 63;
  const int w    = tid >> 6;            // wave index == gate index
  const int g    = blockIdx.x & 7;      // group (16 batch rows) — XCD-aligned
  const int j    = blockIdx.x >> 3;     // unit-quarter: units [64j, 64j+64)
  const int l15  = lane & 15, l16 = lane >> 4;
  constexpr int KTIN = KIN / 32;

  const int colb = w * NH + j * 64;     // gate-column base for this wave

  // Resident W frags (B-operand): cols colb+[0,64), K = KIN
  bf16x8 wfr[KTIN][4];
#pragma unroll
  for (int kt = 0; kt < KTIN; ++kt) {
    const int k0 = kt * 32 + l16 * 8;
#pragma unroll
    for (int nt = 0; nt < 4; ++nt) {
      const float* wp = W + (long)k0 * NG + colb + nt * 16 + l15;
      union { u16 s[8]; bf16x8 v; } cv;
#pragma unroll
      for (int e = 0; e < 8; ++e) cv.s[e] = f2bf(wp[(long)e * NG]);
      wfr[kt][nt] = cv.v;
    }
  }
  // Resident U frags (B-operand): cols colb+[0,64), K = NH = 256
  bf16x8 ufr[8][4];
#pragma unroll
  for (int kt = 0; kt < 8; ++kt) {
    const int k0 = kt * 32 + l16 * 8;
#pragma unroll
    for (int nt = 0; nt < 4; ++nt) {
      const float* up = U + (long)k0 * NG + colb + nt * 16 + l15;
      union { u16 s[8]; bf16x8 v; } cv;
#pragma unroll
      for (int e = 0; e < 8; ++e) cv.s[e] = f2bf(up[(long)e * NG]);
      ufr[kt][nt] = cv.v;
    }
  }

  // pointwise mapping: thread -> (batch row, 4 units)
  const int prow = tid & 15;
  const int ublk = tid >> 4;            // 0..15
  const int b    = g * 16 + prow;
  const int ucol = j * 64 + ublk * 4;   // unit base within [0,256)

  // bias for this thread's 4 units x 4 gates
  float bv[4][4];
#pragma unroll
  for (int gg = 0; gg < 4; ++gg)
#pragma unroll
    for (int q = 0; q < 4; ++q) bv[gg][q] = bias[gg * NH + ucol + q];

  float c[4] = {0.f, 0.f, 0.f, 0.f};
  __shared__ __align__(16) float gl[4][16][68];

  u32* cnt = flags + g;
  const long hb_par = 8L * 16 * NH;     // parity stride in u16
  bool dead = false;

  for (int t = 0; t < NT; ++t) {
    // ---- issue x_t A-frag loads (no h dependence; overlaps the spin) ----
    const long xrow = (long)(g * 16 + l15) * NT + t;
    bf16x8 ax[KTIN];
    f32x4 xraw[KTIN][2];
    if constexpr (XF32) {
#pragma unroll
      for (int kt = 0; kt < KTIN; ++kt) {
        const float* xp = xf + xrow * KIN + kt * 32 + l16 * 8;
        xraw[kt][0] = *reinterpret_cast<const f32x4*>(xp);
        xraw[kt][1] = *reinterpret_cast<const f32x4*>(xp + 4);
      }
    } else {
#pragma unroll
      for (int kt = 0; kt < KTIN; ++kt)
        ax[kt] = *reinterpret_cast<const bf16x8*>(xh + xrow * KIN + kt * 32 + l16 * 8);
    }

    // ---- wait for h_{t-1} from the other 3 WGs of this group ----
    if (t > 0) {
      if (tid == 0 && !dead) {
        const u32 target = 4u * (u32)t;
        int tries = 0;
        while (__hip_atomic_load(cnt, __ATOMIC_ACQUIRE, __HIP_MEMORY_SCOPE_AGENT) < target) {
          if (++tries > 2000000) { dead = true; break; }   // bail, never hang
        }
      }
      __syncthreads();
    }

    // ---- issue h_{t-1} A-frag loads (device-coherent) ----
    bf16x8 af[8];
    if (t > 0) {
      u64* hb = reinterpret_cast<u64*>(hbuf + (long)((t + 1) & 1) * hb_par)
              + (long)g * 1024 + (long)l15 * 64;
#pragma unroll
      for (int kt = 0; kt < 8; ++kt) {
        const int q0 = (kt * 32 + l16 * 8) >> 2;
        u64 lo = __hip_atomic_load(hb + q0,     __ATOMIC_RELAXED, __HIP_MEMORY_SCOPE_AGENT);
        u64 hi = __hip_atomic_load(hb + q0 + 1, __ATOMIC_RELAXED, __HIP_MEMORY_SCOPE_AGENT);
        union { u64 q[2]; bf16x8 v; } cv; cv.q[0] = lo; cv.q[1] = hi;
        af[kt] = cv.v;
      }
    }

    // ---- convert x frags (fp32 path) ----
    if constexpr (XF32) {
#pragma unroll
      for (int kt = 0; kt < KTIN; ++kt) {
        union { u16 s[8]; bf16x8 v; } cv;
#pragma unroll
        for (int e = 0; e < 4; ++e) cv.s[e]     = f2bf(xraw[kt][0][e]);
#pragma unroll
        for (int e = 0; e < 4; ++e) cv.s[4 + e] = f2bf(xraw[kt][1][e]);
        ax[kt] = cv.v;
      }
    }

    // ---- MFMAs: x_t @ W, then h_{t-1} @ U ----
    f32x4 acc[4] = {};
#pragma unroll
    for (int kt = 0; kt < KTIN; ++kt)
#pragma unroll
      for (int nt = 0; nt < 4; ++nt)
        acc[nt] = mm(ax[kt], wfr[kt][nt], acc[nt]);
    if (t > 0) {
#pragma unroll
      for (int kt = 0; kt < 8; ++kt)
#pragma unroll
        for (int nt = 0; nt < 4; ++nt)
          acc[nt] = mm(af[kt], ufr[kt][nt], acc[nt]);
    }

    // ---- gate tiles -> LDS (cross-wave exchange) ----
#pragma unroll
    for (int nt = 0; nt < 4; ++nt)
#pragma unroll
      for (int r = 0; r < 4; ++r)
        gl[w][l16 * 4 + r][nt * 16 + l15] = acc[nt][r];
    __syncthreads();

    // ---- pointwise LSTM cell update (Keras order i, f, cbar, o) ----
    f32x4 gi = *reinterpret_cast<const f32x4*>(&gl[0][prow][ublk * 4]);
    f32x4 gf = *reinterpret_cast<const f32x4*>(&gl[1][prow][ublk * 4]);
    f32x4 gc = *reinterpret_cast<const f32x4*>(&gl[2][prow][ublk * 4]);
    f32x4 go = *reinterpret_cast<const f32x4*>(&gl[3][prow][ublk * 4]);
    float hh[4];
#pragma unroll
    for (int q = 0; q < 4; ++q) {
      float iv = sigm(gi[q] + bv[0][q]);
      float fv = sigm(gf[q] + bv[1][q]);
      float cd = tanh_(gc[q] + bv[2][q]);
      float ov = sigm(go[q] + bv[3][q]);
      c[q] = fv * c[q] + iv * cd;
      hh[q] = ov * tanh_(c[q]);
    }
    union { u16 s[4]; u64 q; } hp;
#pragma unroll
    for (int q = 0; q < 4; ++q) hp.s[q] = f2bf(hh[q]);

    // ---- publish h_t chunk (device-coherent), parity t&1 ----
    u64* hw = reinterpret_cast<u64*>(hbuf + (long)(t & 1) * hb_par)
            + ((long)g * 16 * NH + (long)prow * NH + ucol) / 4;
    __hip_atomic_store(hw, hp.q, __ATOMIC_RELAXED, __HIP_MEMORY_SCOPE_AGENT);

    if (h_seq)
      *reinterpret_cast<u64*>(h_seq + ((long)b * NT + t) * NH + ucol) = hp.q;
    if (hlast && t == NT - 1)
      *reinterpret_cast<f32x4*>(hlast + (long)b * NH + ucol) = f32x4{hh[0], hh[1], hh[2], hh[3]};

    __syncthreads();   // drains all h stores before arrival
    if (tid == 0)
      __hip_atomic_fetch_add(cnt, 1u, __ATOMIC_RELEASE, __HIP_MEMORY_SCOPE_AGENT);
  }
}

// ---------------------------------------------------------------------------
// dense head: out[b] = relu(hlast[b,:] . Wd + bd)
// ---------------------------------------------------------------------------
__global__ void dense_out(const float* __restrict__ hl, const float* __restrict__ Wd,
                          const float* __restrict__ bd, float* __restrict__ out) {
  int b = blockIdx.x, l = threadIdx.x;
  f32x4 h  = *reinterpret_cast<const f32x4*>(hl + (long)b * NH + l * 4);
  f32x4 wv = *reinterpret_cast<const f32x4*>(Wd + l * 4);
  float s = h[0] * wv[0] + h[1] * wv[1] + h[2] * wv[2] + h[3] * wv[3];
#pragma unroll
  for (int off = 32; off > 0; off >>= 1) s += __shfl_down(s, off);
  if (l == 0) out[b] = fmaxf(s + bd[0], 0.f);
}

// ---------------------------------------------------------------------------
extern "C" void kernel_launch(void* const* d_in, const int* in_sizes, int n_in,
                              void* d_out, int out_size, void* d_ws, size_t ws_size,
                              hipStream_t stream) {
  const float* x  = (const float*)d_in[0];
  const float* W1 = (const float*)d_in[1];
  const float* U1 = (const float*)d_in[2];
  const float* b1 = (const float*)d_in[3];
  const float* W2 = (const float*)d_in[4];
  const float* U2 = (const float*)d_in[5];
  const float* b2 = (const float*)d_in[6];
  const float* Wd = (const float*)d_in[7];
  const float* bd = (const float*)d_in[8];
  float* out = (float*)d_out;

  char* ws = (char*)d_ws;
  size_t off = 0;
  auto alloc = [&](size_t bytes) -> char* {
    char* p = ws + off;
    off = (off + bytes + 255) & ~(size_t)255;
    return p;
  };
  u16*   h_seq = (u16*)  alloc((size_t)M_ROWS * NH * 2);       // 64 MiB
  u16*   hbuf  = (u16*)  alloc((size_t)2 * 8 * 16 * NH * 2);   // 128 KiB
  float* hlast = (float*)alloc((size_t)NB * NH * 4);           // 128 KiB
  u32*   flags = (u32*)  alloc(128);

  if (off > ws_size) {
    // workspace too small: finite sentinel 0x42424242 ~= 48.56 (NOT NaN)
    hipMemsetAsync(d_out, 0x42, (size_t)out_size * sizeof(float), stream);
    return;
  }

  prep<<<1, 64, 0, stream>>>(flags);
  lstm_scan<NF, true ><<<32, 256, 0, stream>>>(U1, W1, b1, x, nullptr,
                                               hbuf, flags,      h_seq, nullptr);
  lstm_scan<NH, false><<<32, 256, 0, stream>>>(U2, W2, b2, nullptr, h_seq,
                                               hbuf, flags + 16, nullptr, hlast);
  dense_out<<<128, 64, 0, stream>>>(hlast, Wd, bd, out);
}